// Round 2
// baseline (256.451 us; speedup 1.0000x reference)
//
#include <hip/hip_runtime.h>

#define NCLS 21
#define HW (512 * 512)
#define BATCH 8
#define GRIDX 128                         // blocks per image
#define BLOCK 256
#define QUADS_PER_BLOCK ((HW / 4) / GRIDX)   // 512 quads
#define ITERS (QUADS_PER_BLOCK / BLOCK)      // 2 iterations of 256 threads

// ws layout (floats): [0 .. 167] union[b][c], [168 .. 335] intersect[b][c]
#define WS_FLOATS (2 * BATCH * NCLS)

__global__ void zero_ws_kernel(float* ws) {
    int i = blockIdx.x * blockDim.x + threadIdx.x;
    if (i < WS_FLOATS) ws[i] = 0.0f;
}

__global__ __launch_bounds__(BLOCK) void iou_partial_kernel(
        const float* __restrict__ in,   // [B, C, H, W]
        const int* __restrict__ tgt,    // [B, H, W]
        float* __restrict__ ws) {
    const int b = blockIdx.y;
    const float4* __restrict__ in4 = (const float4*)(in + (size_t)b * NCLS * HW);
    const int4*   __restrict__ tb4 = (const int4*)(tgt + (size_t)b * HW);

    float u_acc[NCLS];
    float i_acc[NCLS];
    #pragma unroll
    for (int c = 0; c < NCLS; ++c) { u_acc[c] = 0.0f; i_acc[c] = 0.0f; }

    const int qbase = blockIdx.x * QUADS_PER_BLOCK;

    for (int it = 0; it < ITERS; ++it) {
        const int q = qbase + it * BLOCK + threadIdx.x;   // quad index (4 pixels)
        const int4 tq = tb4[q];
        const int t[4] = {tq.x, tq.y, tq.z, tq.w};

        // Online softmax state per pixel slot: running max m, running sum s
        // (scaled to current m), argmax am, target logit vt.
        float m[4], s[4], vt[4];
        int   am[4];

        {   // class 0 init
            const float4 x = in4[q];
            const float v[4] = {x.x, x.y, x.z, x.w};
            #pragma unroll
            for (int j = 0; j < 4; ++j) {
                m[j] = v[j]; s[j] = 1.0f; am[j] = 0; vt[j] = v[j];
            }
        }
        #pragma unroll
        for (int c = 1; c < NCLS; ++c) {
            const float4 x = in4[(size_t)c * (HW / 4) + q];
            const float v[4] = {x.x, x.y, x.z, x.w};
            #pragma unroll
            for (int j = 0; j < 4; ++j) {
                const float mn = fmaxf(m[j], v[j]);
                // branchless online-softmax update (one of the exps is exp(0)=1)
                s[j] = s[j] * __expf(m[j] - mn) + __expf(v[j] - mn);
                am[j] = (v[j] > m[j]) ? c : am[j];   // strict > keeps first index
                m[j] = mn;
                vt[j] = (c == t[j]) ? v[j] : vt[j];
            }
        }

        #pragma unroll
        for (int j = 0; j < 4; ++j) {
            const float inv    = 1.0f / s[j];
            const float p_pred = inv;                     // exp(m-m)/s
            const float p_t    = __expf(vt[j] - m[j]) * inv;
            const int   tj = t[j], aj = am[j];
            const float w_t = (tj == aj) ? 0.0f : p_t;    // union 2->1 clamp
            const float ip  = (tj == aj) ? p_pred : 0.0f;
            #pragma unroll
            for (int c = 0; c < NCLS; ++c) {
                u_acc[c] += ((c == aj) ? p_pred : 0.0f) + ((c == tj) ? w_t : 0.0f);
                i_acc[c] += (c == aj) ? ip : 0.0f;
            }
        }
    }

    // 64-lane butterfly reduce of all 42 accumulators
    #pragma unroll
    for (int c = 0; c < NCLS; ++c) {
        #pragma unroll
        for (int off = 32; off > 0; off >>= 1) {
            u_acc[c] += __shfl_down(u_acc[c], off, 64);
            i_acc[c] += __shfl_down(i_acc[c], off, 64);
        }
    }

    __shared__ float s_u[NCLS];
    __shared__ float s_i[NCLS];
    if (threadIdx.x < NCLS) { s_u[threadIdx.x] = 0.0f; s_i[threadIdx.x] = 0.0f; }
    __syncthreads();
    if ((threadIdx.x & 63) == 0) {
        #pragma unroll
        for (int c = 0; c < NCLS; ++c) {
            atomicAdd(&s_u[c], u_acc[c]);
            atomicAdd(&s_i[c], i_acc[c]);
        }
    }
    __syncthreads();
    if (threadIdx.x < NCLS) {
        atomicAdd(&ws[b * NCLS + threadIdx.x], s_u[threadIdx.x]);
        atomicAdd(&ws[BATCH * NCLS + b * NCLS + threadIdx.x], s_i[threadIdx.x]);
    }
}

__global__ __launch_bounds__(BLOCK) void finalize_kernel(
        const float* __restrict__ ws, float* __restrict__ out) {
    __shared__ float red[BLOCK];
    const int i = threadIdx.x;
    float val = 0.0f;
    if (i < BATCH * NCLS) {
        const float u  = ws[i];
        const float it = ws[BATCH * NCLS + i];
        const float ratio = it / fmaxf(u, 1.0f);
        const float d = ratio - 1.0f;
        val = d * d;
    }
    red[i] = val;
    __syncthreads();
    for (int off = BLOCK / 2; off > 0; off >>= 1) {
        if (i < off) red[i] += red[i + off];
        __syncthreads();
    }
    if (i == 0) out[0] = red[0] / (float)BATCH;
}

extern "C" void kernel_launch(void* const* d_in, const int* in_sizes, int n_in,
                              void* d_out, int out_size, void* d_ws, size_t ws_size,
                              hipStream_t stream) {
    const float* in  = (const float*)d_in[0];
    const int*   tgt = (const int*)d_in[1];
    float* ws  = (float*)d_ws;
    float* out = (float*)d_out;

    zero_ws_kernel<<<1, 512, 0, stream>>>(ws);
    dim3 grid(GRIDX, BATCH);
    iou_partial_kernel<<<grid, BLOCK, 0, stream>>>(in, tgt, ws);
    finalize_kernel<<<1, BLOCK, 0, stream>>>(ws, out);
}